// Round 11
// baseline (689.822 us; speedup 1.0000x reference)
//
#include <hip/hip_runtime.h>
#include <hip/hip_bf16.h>

#define CIN  32
#define COUT 64
#define KVOL 27
#define FEPS 1e-5f

typedef __attribute__((ext_vector_type(8))) short short8;
typedef __attribute__((ext_vector_type(4))) float f32x4;

// ws float layout:
// [0,32) sums   [32,64) sumsq   [64,96) scale   [96,128) bias
// [128, 128+27648)  Bf: bf16 B-fragments, uint4[27][4][64] = 110592 B
// [27776, 27776+N*16)  xh bf16-packed [N][32ch] (64B per row)

__device__ __forceinline__ unsigned bfr(float f) {   // f32 -> bf16 bits, RNE
    unsigned u = __float_as_uint(f);
    return (u + 0x7FFFu + ((u >> 16) & 1u)) >> 16;
}

__global__ void k_zero(float* __restrict__ ws) {
    if (threadIdx.x < 64) ws[threadIdx.x] = 0.f;
}

__global__ __launch_bounds__(256) void k_reduce(const float* __restrict__ f,
                                                float* __restrict__ ws, int n4) {
    const float4* f4 = (const float4*)f;
    int tid    = blockIdx.x * blockDim.x + threadIdx.x;
    int stride = gridDim.x * blockDim.x;          // multiple of 8
    float4 s = make_float4(0.f, 0.f, 0.f, 0.f);
    float4 q = make_float4(0.f, 0.f, 0.f, 0.f);
    for (int i = tid; i < n4; i += stride) {
        float4 v = f4[i];
        s.x += v.x; s.y += v.y; s.z += v.z; s.w += v.w;
        q.x = fmaf(v.x, v.x, q.x); q.y = fmaf(v.y, v.y, q.y);
        q.z = fmaf(v.z, v.z, q.z); q.w = fmaf(v.w, v.w, q.w);
    }
    __shared__ float ls[64];
    if (threadIdx.x < 64) ls[threadIdx.x] = 0.f;
    __syncthreads();
    int g = threadIdx.x & 7;
    atomicAdd(&ls[g * 4 + 0], s.x); atomicAdd(&ls[g * 4 + 1], s.y);
    atomicAdd(&ls[g * 4 + 2], s.z); atomicAdd(&ls[g * 4 + 3], s.w);
    atomicAdd(&ls[32 + g * 4 + 0], q.x); atomicAdd(&ls[32 + g * 4 + 1], q.y);
    atomicAdd(&ls[32 + g * 4 + 2], q.z); atomicAdd(&ls[32 + g * 4 + 3], q.w);
    __syncthreads();
    if (threadIdx.x < 64) atomicAdd(&ws[threadIdx.x], ls[threadIdx.x]);
}

__global__ void k_final(const float* __restrict__ gamma, const float* __restrict__ beta,
                        float* __restrict__ ws, float invN) {
    int c = threadIdx.x;                          // 32 threads
    float mean = ws[c] * invN;
    float var  = fmaf(-mean, mean, ws[32 + c] * invN);
    float sc   = gamma[c] * rsqrtf(var + FEPS);
    ws[64 + c] = sc;
    ws[96 + c] = fmaf(-mean, sc, beta[c]);
}

// xhat = relu(f*scale+bias) packed to bf16; 8 channels/thread, uint4 stores.
__global__ __launch_bounds__(256) void k_norm(const float* __restrict__ f,
                                              const float* __restrict__ ws,
                                              uint4* __restrict__ xb, int n8) {
    const float4* f4 = (const float4*)f;
    int tid    = blockIdx.x * blockDim.x + threadIdx.x;
    int stride = gridDim.x * blockDim.x;          // multiple of 4
    int g = tid & 3;                              // channel group 8g..8g+7
    float4 s0 = ((const float4*)(ws + 64))[2 * g];
    float4 s1 = ((const float4*)(ws + 64))[2 * g + 1];
    float4 b0 = ((const float4*)(ws + 96))[2 * g];
    float4 b1 = ((const float4*)(ws + 96))[2 * g + 1];
    for (int i = tid; i < n8; i += stride) {
        float4 v0 = f4[2 * i], v1 = f4[2 * i + 1];
        v0.x = fmaxf(fmaf(v0.x, s0.x, b0.x), 0.f);
        v0.y = fmaxf(fmaf(v0.y, s0.y, b0.y), 0.f);
        v0.z = fmaxf(fmaf(v0.z, s0.z, b0.z), 0.f);
        v0.w = fmaxf(fmaf(v0.w, s0.w, b0.w), 0.f);
        v1.x = fmaxf(fmaf(v1.x, s1.x, b1.x), 0.f);
        v1.y = fmaxf(fmaf(v1.y, s1.y, b1.y), 0.f);
        v1.z = fmaxf(fmaf(v1.z, s1.z, b1.z), 0.f);
        v1.w = fmaxf(fmaf(v1.w, s1.w, b1.w), 0.f);
        uint4 r;
        r.x = bfr(v0.x) | (bfr(v0.y) << 16);
        r.y = bfr(v0.z) | (bfr(v0.w) << 16);
        r.z = bfr(v1.x) | (bfr(v1.y) << 16);
        r.w = bfr(v1.z) | (bfr(v1.w) << 16);
        xb[i] = r;
    }
}

// Build bf16 B-fragments for all 27 offsets.
// Lane holds B[k=(lane>>4)*8+e][n=nt*16+(lane&15)] (same convention as the
// A-gather, so any consistent k-permutation cancels).
__global__ __launch_bounds__(256) void k_prep(const float* __restrict__ W,
                                              uint4* __restrict__ Bf) {
    int k    = blockIdx.x;
    int nt   = threadIdx.x >> 6;
    int lane = threadIdx.x & 63;
    int col  = nt * 16 + (lane & 15);
    int kk   = (lane >> 4) * 8;
    const float* Wk = W + (size_t)k * (CIN * COUT);
    unsigned r[4];
#pragma unroll
    for (int e = 0; e < 4; ++e) {
        unsigned lo = bfr(Wk[(kk + 2 * e) * COUT + col]);
        unsigned hi = bfr(Wk[(kk + 2 * e + 1) * COUT + col]);
        r[e] = lo | (hi << 16);
    }
    Bf[(size_t)(k * 4 + nt) * 64 + lane] = make_uint4(r[0], r[1], r[2], r[3]);
}

#define MFMA4(AV, K)                                                          \
    {                                                                         \
        short8 b0 = __builtin_bit_cast(short8, Bs[(K) * 256 + lane]);         \
        short8 b1 = __builtin_bit_cast(short8, Bs[(K) * 256 + 64 + lane]);    \
        short8 b2 = __builtin_bit_cast(short8, Bs[(K) * 256 + 128 + lane]);   \
        short8 b3 = __builtin_bit_cast(short8, Bs[(K) * 256 + 192 + lane]);   \
        acc0 = __builtin_amdgcn_mfma_f32_16x16x32_bf16(AV, b0, acc0, 0, 0, 0);\
        acc1 = __builtin_amdgcn_mfma_f32_16x16x32_bf16(AV, b1, acc1, 0, 0, 0);\
        acc2 = __builtin_amdgcn_mfma_f32_16x16x32_bf16(AV, b2, acc2, 0, 0, 0);\
        acc3 = __builtin_amdgcn_mfma_f32_16x16x32_bf16(AV, b3, acc3, 0, 0, 0);\
    }

// Output-stationary MFMA conv. vs R10: amdgpu_waves_per_eu(4,4) pins the
// register allocator at the LDS-imposed occupancy (16 waves/CU) -> 128-VGPR
// budget -> idx[27] + a[9] stay in registers (R10 spilled them to scratch:
// FETCH 49MB->1.1GB). Persistent blocks stage the 110KB B-table once per CU;
// branch-free batch-9 gather/MFMA stream.
__global__ __launch_bounds__(1024)
__attribute__((amdgpu_waves_per_eu(4, 4)))
void k_conv(const char* __restrict__ xhb,
            const uint4* __restrict__ Bf,
            const int* __restrict__ nbr,
            float* __restrict__ out,
            int n, int ntiles) {
    __shared__ uint4 Bs[KVOL * 256];               // 110592 B
    int lane = threadIdx.x & 63;
    int wv   = threadIdx.x >> 6;                   // wave 0..15

    // one-time stage of the B-fragment table
#pragma unroll
    for (int it = 0; it < 7; ++it) {
        int t = threadIdx.x + it * 1024;
        if (t < KVOL * 256) Bs[t] = Bf[t];
    }
    __syncthreads();

    int gw  = blockIdx.x * 16 + wv;                // global wave slot (0..4095)
    int col = lane & 15;
    int koff = (lane >> 4) * 16;                   // byte offset within 64B row
    const uint4 zero4 = make_uint4(0u, 0u, 0u, 0u);

    for (int t = gw; t < ntiles; t += 4096) {
        int r0 = t * 16;
        int rl = r0 + col;

        // all 27 neighbor indices up-front: 27 independent loads, one latency
        int idx[KVOL];
#pragma unroll
        for (int k = 0; k < KVOL; ++k)
            idx[k] = nbr[(size_t)k * n + rl];

        f32x4 acc0 = {0.f, 0.f, 0.f, 0.f};
        f32x4 acc1 = acc0, acc2 = acc0, acc3 = acc0;

#pragma unroll
        for (int g = 0; g < 3; ++g) {
            uint4 a[9];
#pragma unroll
            for (int j = 0; j < 9; ++j) {
                int s = idx[g * 9 + j];
                s = (s < 0) ? 0 : s;               // row 0 is L1-hot
                a[j] = *(const uint4*)(xhb + ((size_t)s << 6) + koff);
            }
#pragma unroll
            for (int j = 0; j < 9; ++j) {
                uint4 av4 = (idx[g * 9 + j] < 0) ? zero4 : a[j];
                short8 av = __builtin_bit_cast(short8, av4);
                MFMA4(av, g * 9 + j)
            }
        }

        // C/D layout (verified): col = lane&15, row = (lane>>4)*4 + reg
        int rbase = r0 + (lane >> 4) * 4;
        float* op = out + (size_t)rbase * COUT + col;
#pragma unroll
        for (int j = 0; j < 4; ++j) {
            op[j * COUT +  0] = acc0[j];
            op[j * COUT + 16] = acc1[j];
            op[j * COUT + 32] = acc2[j];
            op[j * COUT + 48] = acc3[j];
        }
    }
}

extern "C" void kernel_launch(void* const* d_in, const int* in_sizes, int n_in,
                              void* d_out, int out_size, void* d_ws, size_t ws_size,
                              hipStream_t stream) {
    const float* feat  = (const float*)d_in[0];
    const float* gamma = (const float*)d_in[1];
    const float* beta  = (const float*)d_in[2];
    const float* W     = (const float*)d_in[3];
    const int*   nbr   = (const int*)d_in[4];
    float* out = (float*)d_out;
    float* ws  = (float*)d_ws;

    int n  = in_sizes[0] / CIN;                   // 400000
    int n4 = in_sizes[0] / 4;
    int n8 = in_sizes[0] / 8;
    int ntiles = n / 16;                          // 25000
    uint4* Bf  = (uint4*)(ws + 128);
    uint4* xb  = (uint4*)(ws + 27776);            // bf16 xhat, 64B rows
    char*  xhb = (char*)xb;

    hipLaunchKernelGGL(k_zero,   dim3(1), dim3(64), 0, stream, ws);
    hipLaunchKernelGGL(k_prep,   dim3(KVOL), dim3(256), 0, stream, W, Bf);
    hipLaunchKernelGGL(k_reduce, dim3(512), dim3(256), 0, stream, feat, ws, n4);
    hipLaunchKernelGGL(k_final,  dim3(1), dim3(32), 0, stream, gamma, beta, ws, 1.0f / (float)n);
    hipLaunchKernelGGL(k_norm,   dim3(2048), dim3(256), 0, stream, feat, ws, xb, n8);
    hipLaunchKernelGGL(k_conv,   dim3(256), dim3(1024), 0, stream, xhb, Bf, nbr, out, n, ntiles);
}

// Round 12
// 94.404 us; speedup vs baseline: 7.3071x; 7.3071x over previous
//
#include <hip/hip_runtime.h>
#include <hip/hip_bf16.h>

#define CIN  32
#define COUT 64
#define KVOL 27
#define FEPS 1e-5f

typedef __attribute__((ext_vector_type(8))) short short8;
typedef __attribute__((ext_vector_type(4))) float f32x4;

// ws float layout:
// [0,32) sums   [32,64) sumsq   [64,96) scale   [96,128) bias
// [128, 128+27648)  Bf: bf16 B-fragments, uint4[27][4][64] = 110592 B
// [27776, 27776+N*16)  xh bf16-packed [N][32ch] (64B per row)

__device__ __forceinline__ unsigned bfr(float f) {   // f32 -> bf16 bits, RNE
    unsigned u = __float_as_uint(f);
    return (u + 0x7FFFu + ((u >> 16) & 1u)) >> 16;
}

__global__ void k_zero(float* __restrict__ ws) {
    if (threadIdx.x < 64) ws[threadIdx.x] = 0.f;
}

__global__ __launch_bounds__(256) void k_reduce(const float* __restrict__ f,
                                                float* __restrict__ ws, int n4) {
    const float4* f4 = (const float4*)f;
    int tid    = blockIdx.x * blockDim.x + threadIdx.x;
    int stride = gridDim.x * blockDim.x;          // multiple of 8
    float4 s = make_float4(0.f, 0.f, 0.f, 0.f);
    float4 q = make_float4(0.f, 0.f, 0.f, 0.f);
    for (int i = tid; i < n4; i += stride) {
        float4 v = f4[i];
        s.x += v.x; s.y += v.y; s.z += v.z; s.w += v.w;
        q.x = fmaf(v.x, v.x, q.x); q.y = fmaf(v.y, v.y, q.y);
        q.z = fmaf(v.z, v.z, q.z); q.w = fmaf(v.w, v.w, q.w);
    }
    __shared__ float ls[64];
    if (threadIdx.x < 64) ls[threadIdx.x] = 0.f;
    __syncthreads();
    int g = threadIdx.x & 7;
    atomicAdd(&ls[g * 4 + 0], s.x); atomicAdd(&ls[g * 4 + 1], s.y);
    atomicAdd(&ls[g * 4 + 2], s.z); atomicAdd(&ls[g * 4 + 3], s.w);
    atomicAdd(&ls[32 + g * 4 + 0], q.x); atomicAdd(&ls[32 + g * 4 + 1], q.y);
    atomicAdd(&ls[32 + g * 4 + 2], q.z); atomicAdd(&ls[32 + g * 4 + 3], q.w);
    __syncthreads();
    if (threadIdx.x < 64) atomicAdd(&ws[threadIdx.x], ls[threadIdx.x]);
}

__global__ void k_final(const float* __restrict__ gamma, const float* __restrict__ beta,
                        float* __restrict__ ws, float invN) {
    int c = threadIdx.x;                          // 32 threads
    float mean = ws[c] * invN;
    float var  = fmaf(-mean, mean, ws[32 + c] * invN);
    float sc   = gamma[c] * rsqrtf(var + FEPS);
    ws[64 + c] = sc;
    ws[96 + c] = fmaf(-mean, sc, beta[c]);
}

// xhat = relu(f*scale+bias) packed to bf16; 8 channels/thread, uint4 stores.
__global__ __launch_bounds__(256) void k_norm(const float* __restrict__ f,
                                              const float* __restrict__ ws,
                                              uint4* __restrict__ xb, int n8) {
    const float4* f4 = (const float4*)f;
    int tid    = blockIdx.x * blockDim.x + threadIdx.x;
    int stride = gridDim.x * blockDim.x;          // multiple of 4
    int g = tid & 3;                              // channel group 8g..8g+7
    float4 s0 = ((const float4*)(ws + 64))[2 * g];
    float4 s1 = ((const float4*)(ws + 64))[2 * g + 1];
    float4 b0 = ((const float4*)(ws + 96))[2 * g];
    float4 b1 = ((const float4*)(ws + 96))[2 * g + 1];
    for (int i = tid; i < n8; i += stride) {
        float4 v0 = f4[2 * i], v1 = f4[2 * i + 1];
        v0.x = fmaxf(fmaf(v0.x, s0.x, b0.x), 0.f);
        v0.y = fmaxf(fmaf(v0.y, s0.y, b0.y), 0.f);
        v0.z = fmaxf(fmaf(v0.z, s0.z, b0.z), 0.f);
        v0.w = fmaxf(fmaf(v0.w, s0.w, b0.w), 0.f);
        v1.x = fmaxf(fmaf(v1.x, s1.x, b1.x), 0.f);
        v1.y = fmaxf(fmaf(v1.y, s1.y, b1.y), 0.f);
        v1.z = fmaxf(fmaf(v1.z, s1.z, b1.z), 0.f);
        v1.w = fmaxf(fmaf(v1.w, s1.w, b1.w), 0.f);
        uint4 r;
        r.x = bfr(v0.x) | (bfr(v0.y) << 16);
        r.y = bfr(v0.z) | (bfr(v0.w) << 16);
        r.z = bfr(v1.x) | (bfr(v1.y) << 16);
        r.w = bfr(v1.z) | (bfr(v1.w) << 16);
        xb[i] = r;
    }
}

// Build bf16 B-fragments for all 27 offsets.
// Lane holds B[k=(lane>>4)*8+e][n=nt*16+(lane&15)] (same convention as the
// A-gather, so any consistent k-permutation cancels).
__global__ __launch_bounds__(256) void k_prep(const float* __restrict__ W,
                                              uint4* __restrict__ Bf) {
    int k    = blockIdx.x;
    int nt   = threadIdx.x >> 6;
    int lane = threadIdx.x & 63;
    int col  = nt * 16 + (lane & 15);
    int kk   = (lane >> 4) * 8;
    const float* Wk = W + (size_t)k * (CIN * COUT);
    unsigned r[4];
#pragma unroll
    for (int e = 0; e < 4; ++e) {
        unsigned lo = bfr(Wk[(kk + 2 * e) * COUT + col]);
        unsigned hi = bfr(Wk[(kk + 2 * e + 1) * COUT + col]);
        r[e] = lo | (hi << 16);
    }
    Bf[(size_t)(k * 4 + nt) * 64 + lane] = make_uint4(r[0], r[1], r[2], r[3]);
}

// ---- 27 named registers via macros (NO arrays -> nothing can be demoted
// to scratch; R10/R11's 1.1GB FETCH was exactly that failure mode). ----
#define GROUP_A(X) X(0,A) X(1,B) X(2,A) X(3,B) X(4,A) X(5,B) X(6,A) X(7,B) X(8,A)
#define GROUP_B(X) X(9,B) X(10,A) X(11,B) X(12,A) X(13,B) X(14,A) X(15,B) X(16,A) X(17,B)
#define GROUP_C(X) X(18,A) X(19,B) X(20,A) X(21,B) X(22,A) X(23,B) X(24,A) X(25,B) X(26,A)

#define KDECL(K,P) int idx##K; uint4 ga##K;
#define KIDX(K,P)  idx##K = nbrl[(size_t)(K) * n];
#define KGATH(K,P) ga##K = *(const uint4*)(xhb + ((size_t)((idx##K < 0) ? 0 : idx##K) << 6) + koff);
// pin: value must be live here -> compiler cannot sink the load into the
// ballot-guarded consume block (which would re-serialize the batch)
#define KPIN(K,P)  asm volatile("" : "+v"(ga##K.x), "+v"(ga##K.y), "+v"(ga##K.z), "+v"(ga##K.w));
#define KCONS(K,P) { uint4 z##K = (idx##K < 0) ? zero4 : ga##K;                                 \
    if (__ballot(idx##K >= 0)) {                                                                \
        short8 av = __builtin_bit_cast(short8, z##K);                                           \
        short8 b0 = __builtin_bit_cast(short8, Bs[(K) * 256 + lane]);                           \
        short8 b1 = __builtin_bit_cast(short8, Bs[(K) * 256 + 64 + lane]);                      \
        short8 b2 = __builtin_bit_cast(short8, Bs[(K) * 256 + 128 + lane]);                     \
        short8 b3 = __builtin_bit_cast(short8, Bs[(K) * 256 + 192 + lane]);                     \
        acc0##P = __builtin_amdgcn_mfma_f32_16x16x32_bf16(av, b0, acc0##P, 0, 0, 0);            \
        acc1##P = __builtin_amdgcn_mfma_f32_16x16x32_bf16(av, b1, acc1##P, 0, 0, 0);            \
        acc2##P = __builtin_amdgcn_mfma_f32_16x16x32_bf16(av, b2, acc2##P, 0, 0, 0);            \
        acc3##P = __builtin_amdgcn_mfma_f32_16x16x32_bf16(av, b3, acc3##P, 0, 0, 0);            \
    } }

// Output-stationary MFMA conv. 512-thr blocks (8 waves share 110KB LDS ->
// 1 block/CU, 2 waves/SIMD) with __launch_bounds__(512,2) -> 256-VGPR budget.
// Per tile: 27 idx loads issued together, then 27 clamped gathers ALL in
// flight (named registers), then 3 groups of 9 ballot-guarded MFMA consumes.
// 8 split accumulators break the same-acc MFMA dependency chain.
__global__ __launch_bounds__(512, 2) void k_conv(const char* __restrict__ xhb,
                                                 const uint4* __restrict__ Bf,
                                                 const int* __restrict__ nbr,
                                                 float* __restrict__ out,
                                                 int n, int ntiles) {
    __shared__ uint4 Bs[KVOL * 256];               // 110592 B
    int lane = threadIdx.x & 63;
    int wv   = threadIdx.x >> 6;                   // wave 0..7

    // one-time stage of the B-fragment table (persistent block)
    for (int t = threadIdx.x; t < KVOL * 256; t += 512) Bs[t] = Bf[t];
    __syncthreads();

    int gw   = blockIdx.x * 8 + wv;                // global wave slot (0..2047)
    int col  = lane & 15;
    int koff = (lane >> 4) * 16;                   // byte offset within 64B row
    const uint4 zero4 = make_uint4(0u, 0u, 0u, 0u);

    for (int t = gw; t < ntiles; t += 2048) {
        int r0 = t * 16;
        const int* nbrl = nbr + (r0 + col);

        f32x4 zf = {0.f, 0.f, 0.f, 0.f};
        f32x4 acc0A = zf, acc1A = zf, acc2A = zf, acc3A = zf;
        f32x4 acc0B = zf, acc1B = zf, acc2B = zf, acc3B = zf;

        GROUP_A(KDECL) GROUP_B(KDECL) GROUP_C(KDECL)
        GROUP_A(KIDX)  GROUP_B(KIDX)  GROUP_C(KIDX)
        GROUP_A(KGATH) GROUP_B(KGATH) GROUP_C(KGATH)
        GROUP_A(KPIN)
        GROUP_A(KCONS)
        GROUP_B(KPIN)
        GROUP_B(KCONS)
        GROUP_C(KPIN)
        GROUP_C(KCONS)

        f32x4 acc0 = acc0A + acc0B;
        f32x4 acc1 = acc1A + acc1B;
        f32x4 acc2 = acc2A + acc2B;
        f32x4 acc3 = acc3A + acc3B;

        // C/D layout (verified): col = lane&15, row = (lane>>4)*4 + reg
        int rbase = r0 + (lane >> 4) * 4;
        float* op = out + (size_t)rbase * COUT + col;
#pragma unroll
        for (int j = 0; j < 4; ++j) {
            op[j * COUT +  0] = acc0[j];
            op[j * COUT + 16] = acc1[j];
            op[j * COUT + 32] = acc2[j];
            op[j * COUT + 48] = acc3[j];
        }
    }
}

extern "C" void kernel_launch(void* const* d_in, const int* in_sizes, int n_in,
                              void* d_out, int out_size, void* d_ws, size_t ws_size,
                              hipStream_t stream) {
    const float* feat  = (const float*)d_in[0];
    const float* gamma = (const float*)d_in[1];
    const float* beta  = (const float*)d_in[2];
    const float* W     = (const float*)d_in[3];
    const int*   nbr   = (const int*)d_in[4];
    float* out = (float*)d_out;
    float* ws  = (float*)d_ws;

    int n  = in_sizes[0] / CIN;                   // 400000
    int n4 = in_sizes[0] / 4;
    int n8 = in_sizes[0] / 8;
    int ntiles = n / 16;                          // 25000
    uint4* Bf  = (uint4*)(ws + 128);
    uint4* xb  = (uint4*)(ws + 27776);            // bf16 xhat, 64B rows
    char*  xhb = (char*)xb;

    hipLaunchKernelGGL(k_zero,   dim3(1), dim3(64), 0, stream, ws);
    hipLaunchKernelGGL(k_prep,   dim3(KVOL), dim3(256), 0, stream, W, Bf);
    hipLaunchKernelGGL(k_reduce, dim3(512), dim3(256), 0, stream, feat, ws, n4);
    hipLaunchKernelGGL(k_final,  dim3(1), dim3(32), 0, stream, gamma, beta, ws, 1.0f / (float)n);
    hipLaunchKernelGGL(k_norm,   dim3(2048), dim3(256), 0, stream, feat, ws, xb, n8);
    hipLaunchKernelGGL(k_conv,   dim3(256), dim3(512), 0, stream, xhb, Bf, nbr, out, n, ntiles);
}